// Round 6
// baseline (1310.299 us; speedup 1.0000x reference)
//
#include <hip/hip_runtime.h>
#include <math.h>

// SKA module: B=4, T=4096, D=1024, H=16, r=32, P=64
// Pipeline: gemm(z), gemm(v) -> norms -> Gram partials -> per-head solve
//           -> gemm(zq, reusing v slot) -> per-token 64x32 matvec output.
#define B_ 4
#define T_ 4096
#define H_ 16
#define R_ 32
#define P_ 64
#define D_ 1024
#define NC_ 16
#define RIDGE 1e-3f

// ---------- C[M][N] = A[M][K] @ W[N][K]^T (both row-major, K contiguous) ----
__global__ __launch_bounds__(256) void gemm_nt(const float* __restrict__ A,
                                               const float* __restrict__ W,
                                               float* __restrict__ C,
                                               int M, int N, int K) {
  __shared__ alignas(16) float As[16][64];  // K-major for float4 inner reads
  __shared__ alignas(16) float Ws[16][64];
  const int tid = threadIdx.x;
  const int tx = tid & 15, ty = tid >> 4;
  const int m0 = blockIdx.y * 64, n0 = blockIdx.x * 64;
  const int lrow = tid >> 2;        // 0..63
  const int lk = (tid & 3) * 4;     // 0,4,8,12
  float c[4][4] = {};
  for (int k0 = 0; k0 < K; k0 += 16) {
    float4 a = *reinterpret_cast<const float4*>(&A[(size_t)(m0 + lrow) * K + k0 + lk]);
    float4 w = *reinterpret_cast<const float4*>(&W[(size_t)(n0 + lrow) * K + k0 + lk]);
    As[lk + 0][lrow] = a.x; As[lk + 1][lrow] = a.y; As[lk + 2][lrow] = a.z; As[lk + 3][lrow] = a.w;
    Ws[lk + 0][lrow] = w.x; Ws[lk + 1][lrow] = w.y; Ws[lk + 2][lrow] = w.z; Ws[lk + 3][lrow] = w.w;
    __syncthreads();
#pragma unroll
    for (int kk = 0; kk < 16; ++kk) {
      float4 a4 = *reinterpret_cast<const float4*>(&As[kk][ty * 4]);
      float4 b4 = *reinterpret_cast<const float4*>(&Ws[kk][tx * 4]);
      float ar[4] = {a4.x, a4.y, a4.z, a4.w};
      float br[4] = {b4.x, b4.y, b4.z, b4.w};
#pragma unroll
      for (int i = 0; i < 4; ++i)
#pragma unroll
        for (int j = 0; j < 4; ++j) c[i][j] = fmaf(ar[i], br[j], c[i][j]);
    }
    __syncthreads();
  }
#pragma unroll
  for (int i = 0; i < 4; ++i) {
    float4 st = make_float4(c[i][0], c[i][1], c[i][2], c[i][3]);
    *reinterpret_cast<float4*>(&C[(size_t)(m0 + ty * 4 + i) * N + n0 + tx * 4]) = st;
  }
}

// ---------- per-(b,h) max over T of ||z_raw[t]||, clipped ----------
__global__ __launch_bounds__(256) void norm_kernel(const float* __restrict__ z,
                                                   float* __restrict__ maxn,
                                                   float* __restrict__ invn) {
  const int bh = blockIdx.x;
  const int b = bh >> 4, hh = bh & 15;
  const size_t zb = (size_t)b * T_ * (H_ * R_) + (size_t)hh * R_;
  float mx = 0.f;
  for (int t = threadIdx.x; t < T_; t += 256) {
    const float4* p = reinterpret_cast<const float4*>(&z[zb + (size_t)t * (H_ * R_)]);
    float s = 0.f;
#pragma unroll
    for (int j = 0; j < 8; ++j) {
      float4 q = p[j];
      s = fmaf(q.x, q.x, s); s = fmaf(q.y, q.y, s);
      s = fmaf(q.z, q.z, s); s = fmaf(q.w, q.w, s);
    }
    mx = fmaxf(mx, s);
  }
  __shared__ float red[256];
  red[threadIdx.x] = mx;
  __syncthreads();
  for (int s = 128; s > 0; s >>= 1) {
    if (threadIdx.x < s) red[threadIdx.x] = fmaxf(red[threadIdx.x], red[threadIdx.x + s]);
    __syncthreads();
  }
  if (threadIdx.x == 0) {
    float mn = fmaxf(sqrtf(red[0]), 1e-6f);
    maxn[bh] = mn;
    invn[bh] = 1.f / mn;
  }
}

// ---------- per-(b,h,chunk): partial G (32x32), M_cov (32x32), C_v (64x32) --
__global__ __launch_bounds__(256) void accum_kernel(const float* __restrict__ z,
                                                    const float* __restrict__ v,
                                                    const int* __restrict__ pmask,
                                                    const float* __restrict__ invn,
                                                    float* __restrict__ Gp,
                                                    float* __restrict__ Mp,
                                                    float* __restrict__ Cp) {
  const int bh = blockIdx.x;
  const int chunk = blockIdx.y;
  const int b = bh >> 4, hh = bh & 15;
  const int tid = threadIdx.x;
  __shared__ alignas(16) float zs[65][32];  // zs[i] = z_norm[t0-1+i]
  __shared__ alignas(16) float vs[64][64];  // vs[i] = v[t0+i]
  __shared__ float ms[65];
  const float inv = invn[bh];
  const int r_gm = tid >> 3;        // 0..31 (row of G/M, col of C_v)
  const int s0 = (tid & 7) * 4;     // col group of G/M
  const int p0 = (tid & 7) * 8;     // row group of C_v
  float accG[4] = {0.f, 0.f, 0.f, 0.f};
  float accM[4] = {0.f, 0.f, 0.f, 0.f};
  float accC[8] = {0.f, 0.f, 0.f, 0.f, 0.f, 0.f, 0.f, 0.f};
  const size_t zb = (size_t)b * T_ * (H_ * R_) + (size_t)hh * R_;
  const size_t vb = (size_t)b * T_ * (H_ * P_) + (size_t)hh * P_;
  const int tstart = chunk * 256;
  for (int tile = 0; tile < 4; ++tile) {
    const int t0 = tstart + tile * 64;
    for (int idx = tid; idx < 65 * 32; idx += 256) {
      int i = idx >> 5, r = idx & 31;
      int t = t0 - 1 + i;
      zs[i][r] = (t >= 0) ? z[zb + (size_t)t * (H_ * R_) + r] * inv : 0.f;
    }
    if (tid < 65) {
      int t = t0 - 1 + tid;
      ms[tid] = (t >= 0) ? (float)pmask[b * T_ + t] : 0.f;
    }
    for (int idx = tid; idx < 64 * 64; idx += 256) {
      int i = idx >> 6, p = idx & 63;
      vs[i][p] = v[vb + (size_t)(t0 + i) * (H_ * P_) + p];
    }
    __syncthreads();
    float4 prev = *reinterpret_cast<const float4*>(&zs[0][s0]);
    for (int i = 1; i <= 64; ++i) {
      float mc = ms[i];
      float ml = mc * ms[i - 1];
      float zr = zs[i][r_gm];
      float4 cur = *reinterpret_cast<const float4*>(&zs[i][s0]);
      float gz = mc * zr;   // mask is 0/1 so m^2 = m
      float mz = ml * zr;
      accG[0] = fmaf(gz, cur.x, accG[0]);
      accG[1] = fmaf(gz, cur.y, accG[1]);
      accG[2] = fmaf(gz, cur.z, accG[2]);
      accG[3] = fmaf(gz, cur.w, accG[3]);
      accM[0] = fmaf(mz, prev.x, accM[0]);   // M[r][s] += z[t][r]*z[t-1][s]*ml
      accM[1] = fmaf(mz, prev.y, accM[1]);
      accM[2] = fmaf(mz, prev.z, accM[2]);
      accM[3] = fmaf(mz, prev.w, accM[3]);
      float4 va = *reinterpret_cast<const float4*>(&vs[i - 1][p0]);
      float4 vb4 = *reinterpret_cast<const float4*>(&vs[i - 1][p0 + 4]);
      accC[0] = fmaf(gz, va.x, accC[0]);     // C[p][r] += m*v[p]*z[r]
      accC[1] = fmaf(gz, va.y, accC[1]);
      accC[2] = fmaf(gz, va.z, accC[2]);
      accC[3] = fmaf(gz, va.w, accC[3]);
      accC[4] = fmaf(gz, vb4.x, accC[4]);
      accC[5] = fmaf(gz, vb4.y, accC[5]);
      accC[6] = fmaf(gz, vb4.z, accC[6]);
      accC[7] = fmaf(gz, vb4.w, accC[7]);
      prev = cur;
    }
    __syncthreads();
  }
  const size_t base = (size_t)bh * NC_ + chunk;
  *reinterpret_cast<float4*>(&Gp[base * 1024 + r_gm * 32 + s0]) =
      make_float4(accG[0], accG[1], accG[2], accG[3]);
  *reinterpret_cast<float4*>(&Mp[base * 1024 + r_gm * 32 + s0]) =
      make_float4(accM[0], accM[1], accM[2], accM[3]);
#pragma unroll
  for (int j = 0; j < 8; ++j) Cp[base * 2048 + (size_t)(p0 + j) * 32 + r_gm] = accC[j];
}

// ---------- per-(b,h): Cholesky, solves, power iter -> W_final (64x32) ----
__global__ __launch_bounds__(64) void solve_kernel(const float* __restrict__ Gp,
                                                   const float* __restrict__ Mp,
                                                   const float* __restrict__ Cp,
                                                   const float* __restrict__ invn,
                                                   const float* __restrict__ p_eta,
                                                   const float* __restrict__ p_gamma,
                                                   float* __restrict__ Wf) {
  const int bh = blockIdx.x;
  const int tid = threadIdx.x;
  __shared__ float sG[32][32], sL[32][32], sB1[32][32], sB2[32][32], sA[32][32], sF[32][32];
  __shared__ float sCv[64][32];
  __shared__ float t2a[32][64], t3a[32][64];
  __shared__ float vec1[32], vec2[32];
  __shared__ float scal[2];
  // 1. reduce partials (fixed order -> deterministic)
  for (int idx = tid; idx < 1024; idx += 64) {
    float a = 0.f, m = 0.f;
    for (int c = 0; c < NC_; ++c) {
      a += Gp[((size_t)bh * NC_ + c) * 1024 + idx];
      m += Mp[((size_t)bh * NC_ + c) * 1024 + idx];
    }
    sG[idx >> 5][idx & 31] = a;
    sB1[idx >> 5][idx & 31] = m;   // sB1 = M_cov
  }
  for (int idx = tid; idx < 2048; idx += 64) {
    float a = 0.f;
    for (int c = 0; c < NC_; ++c) a += Cp[((size_t)bh * NC_ + c) * 2048 + idx];
    sCv[idx >> 5][idx & 31] = a;   // sCv[p][r]
  }
  __syncthreads();
  if (tid < 32) sG[tid][tid] += RIDGE;
  __syncthreads();
  // 2. Cholesky of sG -> sL (lower)
  for (int idx = tid; idx < 1024; idx += 64) {
    int r = idx >> 5, c = idx & 31;
    sL[r][c] = (c <= r) ? sG[r][c] : 0.f;
  }
  __syncthreads();
  for (int j = 0; j < 32; ++j) {
    if (tid == 0) {
      float s = sL[j][j];
      for (int k = 0; k < j; ++k) s -= sL[j][k] * sL[j][k];
      sL[j][j] = sqrtf(s);
    }
    __syncthreads();
    if (tid > j && tid < 32) {
      float s = sL[tid][j];
      for (int k = 0; k < j; ++k) s -= sL[tid][k] * sL[j][k];
      sL[tid][j] = s / sL[j][j];
    }
    __syncthreads();
  }
  // 3. Y = L^-1 M_cov -> sB2  (column per thread)
  if (tid < 32) {
    int c = tid;
    for (int i = 0; i < 32; ++i) {
      float s = sB1[i][c];
      for (int k = 0; k < i; ++k) s -= sL[i][k] * sB2[k][c];
      sB2[i][c] = s / sL[i][i];
    }
  }
  __syncthreads();
  // 4. sB1 = Y^T
  for (int idx = tid; idx < 1024; idx += 64) {
    int r = idx >> 5, c = idx & 31;
    sB1[r][c] = sB2[c][r];
  }
  __syncthreads();
  // 5. Z = L^-1 Y^T -> sB2 (in-place ok: only own column's written rows read)
  if (tid < 32) {
    int c = tid;
    for (int i = 0; i < 32; ++i) {
      float s = sB1[i][c];
      for (int k = 0; k < i; ++k) s -= sL[i][k] * sB2[k][c];
      sB2[i][c] = s / sL[i][i];
    }
  }
  __syncthreads();
  // 6. sA = A_w = Z^T  (= L^-1 M_cov L^-T)
  for (int idx = tid; idx < 1024; idx += 64) {
    int r = idx >> 5, c = idx & 31;
    sA[r][c] = sB2[c][r];
  }
  __syncthreads();
  // 7. power iteration (6 iters, exact reference semantics, unscaled A)
  if (tid < 32) vec1[tid] = 0.17677669529663687f;  // 1/sqrt(32)
  __syncthreads();
  for (int it = 0; it < 6; ++it) {
    if (tid < 32) {
      float s = 0.f;
      for (int k = 0; k < 32; ++k) s += sA[tid][k] * vec1[k];
      vec2[tid] = s;
    }
    __syncthreads();
    if (tid == 0) {
      float s = 0.f;
      for (int k = 0; k < 32; ++k) s += vec2[k] * vec2[k];
      scal[0] = fmaxf(sqrtf(s), 1e-8f);
    }
    __syncthreads();
    if (tid < 32) vec2[tid] = vec2[tid] / scal[0];  // u
    __syncthreads();
    if (tid < 32) {
      float s = 0.f;
      for (int k = 0; k < 32; ++k) s += sA[k][tid] * vec2[k];  // A^T u
      vec1[tid] = s;
    }
    __syncthreads();
    if (tid == 0) {
      float s = 0.f;
      for (int k = 0; k < 32; ++k) s += vec1[k] * vec1[k];
      scal[0] = fmaxf(sqrtf(s), 1e-8f);
    }
    __syncthreads();
    if (tid < 32) vec1[tid] = vec1[tid] / scal[0];  // vv
    __syncthreads();
  }
  if (tid < 32) {
    float s = 0.f;
    for (int k = 0; k < 32; ++k) s += sA[tid][k] * vec1[k];
    vec2[tid] = s;
  }
  __syncthreads();
  if (tid == 0) {
    float s = 0.f;
    for (int k = 0; k < 32; ++k) s += vec2[k] * vec2[k];
    scal[1] = fmaxf(sqrtf(s), 1.f);  // scale = max(sigma, 1)
  }
  __syncthreads();
  {
    float gc = fminf(fmaxf(p_gamma[0], 1.f), 1.5f);
    float fct = gc / scal[1];
    for (int idx = tid; idx < 1024; idx += 64) sA[idx >> 5][idx & 31] *= fct;
  }
  __syncthreads();
  // 8. F = A_w @ A_w  (POWER_K=2)
  for (int e = tid; e < 1024; e += 64) {
    int i = e >> 5, j = e & 31;
    float s = 0.f;
    for (int k = 0; k < 32; ++k) s += sA[i][k] * sA[k][j];
    sF[i][j] = s;
  }
  __syncthreads();
  // 9. B1 = L @ F
  for (int e = tid; e < 1024; e += 64) {
    int i = e >> 5, j = e & 31;
    float s = 0.f;
    for (int k = 0; k <= i; ++k) s += sL[i][k] * sF[k][j];
    sB1[i][j] = s;
  }
  __syncthreads();
  // 10. M2 = B1 @ L^-1  via L^T Xt = B1^T ; Xt -> sB2 (M2[r][j] = sB2[j][r])
  if (tid < 32) {
    int c = tid;
    for (int i = 31; i >= 0; --i) {
      float s = sB1[c][i];
      for (int k = i + 1; k < 32; ++k) s -= sL[k][i] * sB2[k][c];
      sB2[i][c] = s / sL[i][i];
    }
  }
  __syncthreads();
  // 11. t2 = L^-1 C_v^T  (64 columns, thread per p)
  {
    int p = tid;
    for (int i = 0; i < 32; ++i) {
      float s = sCv[p][i];
      for (int k = 0; k < i; ++k) s -= sL[i][k] * t2a[k][p];
      t2a[i][p] = s / sL[i][i];
    }
  }
  __syncthreads();
  // 12. t3 = L^-T t2  (B_v[p][r] = t3[r][p])
  {
    int p = tid;
    for (int i = 31; i >= 0; --i) {
      float s = t2a[i][p];
      for (int k = i + 1; k < 32; ++k) s -= sL[k][i] * t3a[k][p];
      t3a[i][p] = s / sL[i][i];
    }
  }
  __syncthreads();
  // 13. W_final[p][j] = eta/max_norm * sum_r B_v[p][r] * M2[r][j]
  {
    float so = p_eta[0] * invn[bh];
    int p = tid;
    for (int j = 0; j < 32; ++j) {
      float s = 0.f;
      for (int r = 0; r < 32; ++r) s += t3a[r][p] * sB2[j][r];
      Wf[(size_t)bh * 2048 + p * 32 + j] = s * so;
    }
  }
}

// ---------- y[b,t,h,:] = W_final[b,h] (64x32) @ zq_raw[b,t,h,:] ----------
__global__ __launch_bounds__(256) void out_kernel(const float* __restrict__ zq,
                                                  const float* __restrict__ Wf,
                                                  float* __restrict__ out) {
  const int bh = blockIdx.x;
  const int chunk = blockIdx.y;
  const int b = bh >> 4, hh = bh & 15;
  const int tid = threadIdx.x;
  __shared__ alignas(16) float sW[64][32];
  for (int idx = tid; idx < 2048; idx += 256) sW[idx >> 5][idx & 31] = Wf[(size_t)bh * 2048 + idx];
  __syncthreads();
  const int t = chunk * 256 + tid;
  const float4* qp = reinterpret_cast<const float4*>(&zq[((size_t)(b * T_ + t) * H_ + hh) * R_]);
  float qs[32];
#pragma unroll
  for (int j = 0; j < 8; ++j) {
    float4 q = qp[j];
    qs[j * 4 + 0] = q.x; qs[j * 4 + 1] = q.y; qs[j * 4 + 2] = q.z; qs[j * 4 + 3] = q.w;
  }
  float* op = &out[((size_t)(b * T_ + t) * H_ + hh) * P_];
  for (int p4 = 0; p4 < 64; p4 += 4) {
    float o[4];
#pragma unroll
    for (int pi = 0; pi < 4; ++pi) {
      const float* wr = sW[p4 + pi];
      float s = 0.f;
#pragma unroll
      for (int k = 0; k < 32; ++k) s = fmaf(wr[k], qs[k], s);
      o[pi] = s;
    }
    *reinterpret_cast<float4*>(&op[p4]) = make_float4(o[0], o[1], o[2], o[3]);
  }
}

extern "C" void kernel_launch(void* const* d_in, const int* in_sizes, int n_in,
                              void* d_out, int out_size, void* d_ws, size_t ws_size,
                              hipStream_t stream) {
  const float* h = (const float*)d_in[0];
  const int* pmask = (const int*)d_in[1];
  const float* Wk = (const float*)d_in[2];
  const float* Wq = (const float*)d_in[3];
  const float* Wv = (const float*)d_in[4];
  const float* eta = (const float*)d_in[5];
  const float* gamma_p = (const float*)d_in[6];
  float* out = (float*)d_out;
  float* ws = (float*)d_ws;

  // workspace layout (floats); zq reuses the v slot after accum consumes v.
  float* z = ws;                               // 8,388,608
  float* v = z + (size_t)8388608;              // 16,777,216
  float* zq = v;                               // alias (v dead after accum)
  float* maxn = v + (size_t)16777216;          // 64
  float* invn = maxn + 64;                     // 64
  float* Gp = invn + 64;                       // 1,048,576
  float* Mp = Gp + (size_t)1048576;            // 1,048,576
  float* Cp = Mp + (size_t)1048576;            // 2,097,152
  float* Wf = Cp + (size_t)2097152;            // 131,072   (total ~118 MB)

  gemm_nt<<<dim3(8, 256), 256, 0, stream>>>(h, Wk, z, 16384, 512, 1024);
  gemm_nt<<<dim3(16, 256), 256, 0, stream>>>(h, Wv, v, 16384, 1024, 1024);
  norm_kernel<<<64, 256, 0, stream>>>(z, maxn, invn);
  accum_kernel<<<dim3(64, 16), 256, 0, stream>>>(z, v, pmask, invn, Gp, Mp, Cp);
  gemm_nt<<<dim3(8, 256), 256, 0, stream>>>(h, Wq, zq, 16384, 512, 1024);
  solve_kernel<<<64, 64, 0, stream>>>(Gp, Mp, Cp, invn, eta, gamma_p, Wf);
  out_kernel<<<dim3(64, 16), 256, 0, stream>>>(zq, Wf, out);
}

// Round 10
// 666.997 us; speedup vs baseline: 1.9645x; 1.9645x over previous
//
#include <hip/hip_runtime.h>
#include <math.h>

// SKA module: B=4, T=4096, D=1024, H=16, r=32, P=64
// R9 (= R8 resubmit): projections via split-bf16 MFMA (hi/lo, 3 products).
#define B_ 4
#define T_ 4096
#define H_ 16
#define R_ 32
#define P_ 64
#define D_ 1024
#define NC_ 16
#define RIDGE 1e-3f

typedef unsigned short u16;
typedef __attribute__((ext_vector_type(8))) short short8;   // 8 bf16 bit-patterns
typedef __attribute__((ext_vector_type(4))) float f32x4;

__device__ __forceinline__ u16 f2bf(float f) {  // RNE float -> bf16 bits
  unsigned int u = __float_as_uint(f);
  unsigned int r = u + 0x7FFFu + ((u >> 16) & 1u);
  return (u16)(r >> 16);
}
__device__ __forceinline__ float bf2f(u16 b) {
  return __uint_as_float(((unsigned int)b) << 16);
}

// ---------- split pass: x(f32) -> hi,lo bf16 bit arrays ----------
__global__ __launch_bounds__(256) void split_kernel(const float* __restrict__ x,
                                                    u16* __restrict__ hi,
                                                    u16* __restrict__ lo, int n4) {
  for (int i = blockIdx.x * 256 + threadIdx.x; i < n4; i += gridDim.x * 256) {
    float4 v = reinterpret_cast<const float4*>(x)[i];
    float xs[4] = {v.x, v.y, v.z, v.w};
    ushort4 hh, ll;
    u16* hp = (u16*)&hh; u16* lp = (u16*)&ll;
#pragma unroll
    for (int j = 0; j < 4; ++j) {
      u16 hb = f2bf(xs[j]);
      hp[j] = hb;
      lp[j] = f2bf(xs[j] - bf2f(hb));
    }
    reinterpret_cast<ushort4*>(hi)[i] = hh;
    reinterpret_cast<ushort4*>(lo)[i] = ll;
  }
}

// ---------- C[M][ldc-slice] = A[M][1024] @ W[N][1024]^T via split-bf16 MFMA --
// PS=true: pre-split bf16 inputs; PS=false: f32 inputs, convert in-kernel.
template <bool PS>
__global__ __launch_bounds__(256) void gemm_mfma(const u16* __restrict__ Ahi,
                                                 const u16* __restrict__ Alo,
                                                 const u16* __restrict__ Whi,
                                                 const u16* __restrict__ Wlo,
                                                 const float* __restrict__ Af,
                                                 const float* __restrict__ Wff,
                                                 float* __restrict__ C, int ldc) {
  __shared__ alignas(16) u16 Ah[128][40];   // +8 pad (2-way bank alias = free)
  __shared__ alignas(16) u16 Al[128][40];
  __shared__ alignas(16) u16 Bh[128][40];
  __shared__ alignas(16) u16 Bl[128][40];
  const int tid = threadIdx.x;
  const int lane = tid & 63;
  const int wave = tid >> 6;                 // 4 waves
  const int wm = wave >> 1, wn = wave & 1;   // 2x2 wave grid, 64x64 each
  const int m0 = blockIdx.y * 128, n0 = blockIdx.x * 128;
  const int fr = lane & 15;                  // fragment row (A) / col (B)
  const int fk = (lane >> 4) * 8;            // fragment k base
  f32x4 acc[4][4] = {};

  for (int k0 = 0; k0 < 1024; k0 += 32) {
    if constexpr (PS) {
#pragma unroll
      for (int it = 0; it < 2; ++it) {
        int s = tid + it * 256;              // 512 slots: 128 rows x 4 groups
        int r = s >> 2, c = (s & 3) * 8;
        size_t ga = (size_t)(m0 + r) * 1024 + k0 + c;
        size_t gw = (size_t)(n0 + r) * 1024 + k0 + c;
        *reinterpret_cast<uint4*>(&Ah[r][c]) = *reinterpret_cast<const uint4*>(&Ahi[ga]);
        *reinterpret_cast<uint4*>(&Al[r][c]) = *reinterpret_cast<const uint4*>(&Alo[ga]);
        *reinterpret_cast<uint4*>(&Bh[r][c]) = *reinterpret_cast<const uint4*>(&Whi[gw]);
        *reinterpret_cast<uint4*>(&Bl[r][c]) = *reinterpret_cast<const uint4*>(&Wlo[gw]);
      }
    } else {
#pragma unroll
      for (int it = 0; it < 4; ++it) {
        int s = tid + it * 256;              // 1024 slots: 128 rows x 8 groups
        int r = s >> 3, c = (s & 7) * 4;
        float4 av = *reinterpret_cast<const float4*>(&Af[(size_t)(m0 + r) * 1024 + k0 + c]);
        float4 wv = *reinterpret_cast<const float4*>(&Wff[(size_t)(n0 + r) * 1024 + k0 + c]);
        float ax[4] = {av.x, av.y, av.z, av.w};
        float wx[4] = {wv.x, wv.y, wv.z, wv.w};
#pragma unroll
        for (int j = 0; j < 4; ++j) {
          u16 hb = f2bf(ax[j]);
          Ah[r][c + j] = hb;
          Al[r][c + j] = f2bf(ax[j] - bf2f(hb));
          u16 wb = f2bf(wx[j]);
          Bh[r][c + j] = wb;
          Bl[r][c + j] = f2bf(wx[j] - bf2f(wb));
        }
      }
    }
    __syncthreads();
    short8 ah[4], al[4];
#pragma unroll
    for (int mi = 0; mi < 4; ++mi) {
      ah[mi] = *reinterpret_cast<const short8*>(&Ah[wm * 64 + mi * 16 + fr][fk]);
      al[mi] = *reinterpret_cast<const short8*>(&Al[wm * 64 + mi * 16 + fr][fk]);
    }
#pragma unroll
    for (int ni = 0; ni < 4; ++ni) {
      short8 bh = *reinterpret_cast<const short8*>(&Bh[wn * 64 + ni * 16 + fr][fk]);
      short8 bl = *reinterpret_cast<const short8*>(&Bl[wn * 64 + ni * 16 + fr][fk]);
#pragma unroll
      for (int mi = 0; mi < 4; ++mi) {
        acc[mi][ni] = __builtin_amdgcn_mfma_f32_16x16x32_bf16(ah[mi], bh, acc[mi][ni], 0, 0, 0);
        acc[mi][ni] = __builtin_amdgcn_mfma_f32_16x16x32_bf16(al[mi], bh, acc[mi][ni], 0, 0, 0);
        acc[mi][ni] = __builtin_amdgcn_mfma_f32_16x16x32_bf16(ah[mi], bl, acc[mi][ni], 0, 0, 0);
      }
    }
    __syncthreads();
  }
  const int cr = (lane >> 4) * 4;            // C/D: col=lane&15, row=(lane>>4)*4+reg
#pragma unroll
  for (int mi = 0; mi < 4; ++mi)
#pragma unroll
    for (int ni = 0; ni < 4; ++ni)
#pragma unroll
      for (int rr = 0; rr < 4; ++rr)
        C[(size_t)(m0 + wm * 64 + mi * 16 + cr + rr) * ldc + (n0 + wn * 64 + ni * 16 + fr)] =
            acc[mi][ni][rr];
}

// ---------- per-(b,h) max over T of ||z_raw[t]||, clipped ----------
__global__ __launch_bounds__(256) void norm_kernel(const float* __restrict__ z,
                                                   float* __restrict__ maxn,
                                                   float* __restrict__ invn) {
  const int bh = blockIdx.x;
  const int b = bh >> 4, hh = bh & 15;
  const size_t zb = (size_t)b * T_ * (H_ * R_) + (size_t)hh * R_;
  float mx = 0.f;
  for (int t = threadIdx.x; t < T_; t += 256) {
    const float4* p = reinterpret_cast<const float4*>(&z[zb + (size_t)t * (H_ * R_)]);
    float s = 0.f;
#pragma unroll
    for (int j = 0; j < 8; ++j) {
      float4 q = p[j];
      s = fmaf(q.x, q.x, s); s = fmaf(q.y, q.y, s);
      s = fmaf(q.z, q.z, s); s = fmaf(q.w, q.w, s);
    }
    mx = fmaxf(mx, s);
  }
  __shared__ float red[256];
  red[threadIdx.x] = mx;
  __syncthreads();
  for (int s = 128; s > 0; s >>= 1) {
    if (threadIdx.x < s) red[threadIdx.x] = fmaxf(red[threadIdx.x], red[threadIdx.x + s]);
    __syncthreads();
  }
  if (threadIdx.x == 0) {
    float mn = fmaxf(sqrtf(red[0]), 1e-6f);
    maxn[bh] = mn;
    invn[bh] = 1.f / mn;
  }
}

// ---------- per-(b,h,chunk): partial G (32x32), M_cov (32x32), C_v (64x32) --
__global__ __launch_bounds__(256) void accum_kernel(const float* __restrict__ z,
                                                    const float* __restrict__ v,
                                                    const int* __restrict__ pmask,
                                                    const float* __restrict__ invn,
                                                    float* __restrict__ Gp,
                                                    float* __restrict__ Mp,
                                                    float* __restrict__ Cp) {
  const int bh = blockIdx.x;
  const int chunk = blockIdx.y;
  const int b = bh >> 4, hh = bh & 15;
  const int tid = threadIdx.x;
  __shared__ alignas(16) float zs[65][32];
  __shared__ alignas(16) float vs[64][64];
  __shared__ float ms[65];
  const float inv = invn[bh];
  const int r_gm = tid >> 3;
  const int s0 = (tid & 7) * 4;
  const int p0 = (tid & 7) * 8;
  float accG[4] = {0.f, 0.f, 0.f, 0.f};
  float accM[4] = {0.f, 0.f, 0.f, 0.f};
  float accC[8] = {0.f, 0.f, 0.f, 0.f, 0.f, 0.f, 0.f, 0.f};
  const size_t zb = (size_t)b * T_ * (H_ * R_) + (size_t)hh * R_;
  const size_t vb = (size_t)b * T_ * (H_ * P_) + (size_t)hh * P_;
  const int tstart = chunk * 256;
  for (int tile = 0; tile < 4; ++tile) {
    const int t0 = tstart + tile * 64;
    for (int idx = tid; idx < 65 * 32; idx += 256) {
      int i = idx >> 5, r = idx & 31;
      int t = t0 - 1 + i;
      zs[i][r] = (t >= 0) ? z[zb + (size_t)t * (H_ * R_) + r] * inv : 0.f;
    }
    if (tid < 65) {
      int t = t0 - 1 + tid;
      ms[tid] = (t >= 0) ? (float)pmask[b * T_ + t] : 0.f;
    }
    for (int idx = tid; idx < 64 * 64; idx += 256) {
      int i = idx >> 6, p = idx & 63;
      vs[i][p] = v[vb + (size_t)(t0 + i) * (H_ * P_) + p];
    }
    __syncthreads();
    float4 prev = *reinterpret_cast<const float4*>(&zs[0][s0]);
    for (int i = 1; i <= 64; ++i) {
      float mc = ms[i];
      float ml = mc * ms[i - 1];
      float zr = zs[i][r_gm];
      float4 cur = *reinterpret_cast<const float4*>(&zs[i][s0]);
      float gz = mc * zr;
      float mz = ml * zr;
      accG[0] = fmaf(gz, cur.x, accG[0]);
      accG[1] = fmaf(gz, cur.y, accG[1]);
      accG[2] = fmaf(gz, cur.z, accG[2]);
      accG[3] = fmaf(gz, cur.w, accG[3]);
      accM[0] = fmaf(mz, prev.x, accM[0]);
      accM[1] = fmaf(mz, prev.y, accM[1]);
      accM[2] = fmaf(mz, prev.z, accM[2]);
      accM[3] = fmaf(mz, prev.w, accM[3]);
      float4 va = *reinterpret_cast<const float4*>(&vs[i - 1][p0]);
      float4 vb4 = *reinterpret_cast<const float4*>(&vs[i - 1][p0 + 4]);
      accC[0] = fmaf(gz, va.x, accC[0]);
      accC[1] = fmaf(gz, va.y, accC[1]);
      accC[2] = fmaf(gz, va.z, accC[2]);
      accC[3] = fmaf(gz, va.w, accC[3]);
      accC[4] = fmaf(gz, vb4.x, accC[4]);
      accC[5] = fmaf(gz, vb4.y, accC[5]);
      accC[6] = fmaf(gz, vb4.z, accC[6]);
      accC[7] = fmaf(gz, vb4.w, accC[7]);
      prev = cur;
    }
    __syncthreads();
  }
  const size_t base = (size_t)bh * NC_ + chunk;
  *reinterpret_cast<float4*>(&Gp[base * 1024 + r_gm * 32 + s0]) =
      make_float4(accG[0], accG[1], accG[2], accG[3]);
  *reinterpret_cast<float4*>(&Mp[base * 1024 + r_gm * 32 + s0]) =
      make_float4(accM[0], accM[1], accM[2], accM[3]);
#pragma unroll
  for (int j = 0; j < 8; ++j) Cp[base * 2048 + (size_t)(p0 + j) * 32 + r_gm] = accC[j];
}

// ---------- per-(b,h): Cholesky, solves, power iter -> W_final (64x32) ----
__global__ __launch_bounds__(64) void solve_kernel(const float* __restrict__ Gp,
                                                   const float* __restrict__ Mp,
                                                   const float* __restrict__ Cp,
                                                   const float* __restrict__ invn,
                                                   const float* __restrict__ p_eta,
                                                   const float* __restrict__ p_gamma,
                                                   float* __restrict__ Wf) {
  const int bh = blockIdx.x;
  const int tid = threadIdx.x;
  __shared__ float sG[32][32], sL[32][32], sB1[32][32], sB2[32][32], sA[32][32], sF[32][32];
  __shared__ float sCv[64][32];
  __shared__ float t2a[32][64], t3a[32][64];
  __shared__ float vec1[32], vec2[32];
  __shared__ float scal[2];
  for (int idx = tid; idx < 1024; idx += 64) {
    float a = 0.f, m = 0.f;
    for (int c = 0; c < NC_; ++c) {
      a += Gp[((size_t)bh * NC_ + c) * 1024 + idx];
      m += Mp[((size_t)bh * NC_ + c) * 1024 + idx];
    }
    sG[idx >> 5][idx & 31] = a;
    sB1[idx >> 5][idx & 31] = m;
  }
  for (int idx = tid; idx < 2048; idx += 64) {
    float a = 0.f;
    for (int c = 0; c < NC_; ++c) a += Cp[((size_t)bh * NC_ + c) * 2048 + idx];
    sCv[idx >> 5][idx & 31] = a;
  }
  __syncthreads();
  if (tid < 32) sG[tid][tid] += RIDGE;
  __syncthreads();
  for (int idx = tid; idx < 1024; idx += 64) {
    int r = idx >> 5, c = idx & 31;
    sL[r][c] = (c <= r) ? sG[r][c] : 0.f;
  }
  __syncthreads();
  for (int j = 0; j < 32; ++j) {
    if (tid == 0) {
      float s = sL[j][j];
      for (int k = 0; k < j; ++k) s -= sL[j][k] * sL[j][k];
      sL[j][j] = sqrtf(s);
    }
    __syncthreads();
    if (tid > j && tid < 32) {
      float s = sL[tid][j];
      for (int k = 0; k < j; ++k) s -= sL[tid][k] * sL[j][k];
      sL[tid][j] = s / sL[j][j];
    }
    __syncthreads();
  }
  if (tid < 32) {
    int c = tid;
    for (int i = 0; i < 32; ++i) {
      float s = sB1[i][c];
      for (int k = 0; k < i; ++k) s -= sL[i][k] * sB2[k][c];
      sB2[i][c] = s / sL[i][i];
    }
  }
  __syncthreads();
  for (int idx = tid; idx < 1024; idx += 64) {
    int r = idx >> 5, c = idx & 31;
    sB1[r][c] = sB2[c][r];
  }
  __syncthreads();
  if (tid < 32) {
    int c = tid;
    for (int i = 0; i < 32; ++i) {
      float s = sB1[i][c];
      for (int k = 0; k < i; ++k) s -= sL[i][k] * sB2[k][c];
      sB2[i][c] = s / sL[i][i];
    }
  }
  __syncthreads();
  for (int idx = tid; idx < 1024; idx += 64) {
    int r = idx >> 5, c = idx & 31;
    sA[r][c] = sB2[c][r];
  }
  __syncthreads();
  if (tid < 32) vec1[tid] = 0.17677669529663687f;
  __syncthreads();
  for (int it = 0; it < 6; ++it) {
    if (tid < 32) {
      float s = 0.f;
      for (int k = 0; k < 32; ++k) s += sA[tid][k] * vec1[k];
      vec2[tid] = s;
    }
    __syncthreads();
    if (tid == 0) {
      float s = 0.f;
      for (int k = 0; k < 32; ++k) s += vec2[k] * vec2[k];
      scal[0] = fmaxf(sqrtf(s), 1e-8f);
    }
    __syncthreads();
    if (tid < 32) vec2[tid] = vec2[tid] / scal[0];
    __syncthreads();
    if (tid < 32) {
      float s = 0.f;
      for (int k = 0; k < 32; ++k) s += sA[k][tid] * vec2[k];
      vec1[tid] = s;
    }
    __syncthreads();
    if (tid == 0) {
      float s = 0.f;
      for (int k = 0; k < 32; ++k) s += vec1[k] * vec1[k];
      scal[0] = fmaxf(sqrtf(s), 1e-8f);
    }
    __syncthreads();
    if (tid < 32) vec1[tid] = vec1[tid] / scal[0];
    __syncthreads();
  }
  if (tid < 32) {
    float s = 0.f;
    for (int k = 0; k < 32; ++k) s += sA[tid][k] * vec1[k];
    vec2[tid] = s;
  }
  __syncthreads();
  if (tid == 0) {
    float s = 0.f;
    for (int k = 0; k < 32; ++k) s += vec2[k] * vec2[k];
    scal[1] = fmaxf(sqrtf(s), 1.f);
  }
  __syncthreads();
  {
    float gc = fminf(fmaxf(p_gamma[0], 1.f), 1.5f);
    float fct = gc / scal[1];
    for (int idx = tid; idx < 1024; idx += 64) sA[idx >> 5][idx & 31] *= fct;
  }
  __syncthreads();
  for (int e = tid; e < 1024; e += 64) {
    int i = e >> 5, j = e & 31;
    float s = 0.f;
    for (int k = 0; k < 32; ++k) s += sA[i][k] * sA[k][j];
    sF[i][j] = s;
  }
  __syncthreads();
  for (int e = tid; e < 1024; e += 64) {
    int i = e >> 5, j = e & 31;
    float s = 0.f;
    for (int k = 0; k <= i; ++k) s += sL[i][k] * sF[k][j];
    sB1[i][j] = s;
  }
  __syncthreads();
  if (tid < 32) {
    int c = tid;
    for (int i = 31; i >= 0; --i) {
      float s = sB1[c][i];
      for (int k = i + 1; k < 32; ++k) s -= sL[k][i] * sB2[k][c];
      sB2[i][c] = s / sL[i][i];
    }
  }
  __syncthreads();
  {
    int p = tid;
    for (int i = 0; i < 32; ++i) {
      float s = sCv[p][i];
      for (int k = 0; k < i; ++k) s -= sL[i][k] * t2a[k][p];
      t2a[i][p] = s / sL[i][i];
    }
  }
  __syncthreads();
  {
    int p = tid;
    for (int i = 31; i >= 0; --i) {
      float s = t2a[i][p];
      for (int k = i + 1; k < 32; ++k) s -= sL[k][i] * t3a[k][p];
      t3a[i][p] = s / sL[i][i];
    }
  }
  __syncthreads();
  {
    float so = p_eta[0] * invn[bh];
    int p = tid;
    for (int j = 0; j < 32; ++j) {
      float s = 0.f;
      for (int r = 0; r < 32; ++r) s += t3a[r][p] * sB2[j][r];
      Wf[(size_t)bh * 2048 + p * 32 + j] = s * so;
    }
  }
}

// ---------- y[b,t,h,:] = W_final[b,h] (64x32) @ zq_raw[b,t,h,:] ----------
__global__ __launch_bounds__(256) void out_kernel(const float* __restrict__ zq,
                                                  const float* __restrict__ Wf,
                                                  float* __restrict__ out) {
  const int bh = blockIdx.x;
  const int chunk = blockIdx.y;
  const int b = bh >> 4, hh = bh & 15;
  const int tid = threadIdx.x;
  __shared__ alignas(16) float sW[64][32];
  for (int idx = tid; idx < 2048; idx += 256) sW[idx >> 5][idx & 31] = Wf[(size_t)bh * 2048 + idx];
  __syncthreads();
  const int t = chunk * 256 + tid;
  const float4* qp = reinterpret_cast<const float4*>(&zq[((size_t)(b * T_ + t) * H_ + hh) * R_]);
  float qs[32];
#pragma unroll
  for (int j = 0; j < 8; ++j) {
    float4 q = qp[j];
    qs[j * 4 + 0] = q.x; qs[j * 4 + 1] = q.y; qs[j * 4 + 2] = q.z; qs[j * 4 + 3] = q.w;
  }
  float* op = &out[((size_t)(b * T_ + t) * H_ + hh) * P_];
  for (int p4 = 0; p4 < 64; p4 += 4) {
    float o[4];
#pragma unroll
    for (int pi = 0; pi < 4; ++pi) {
      const float* wr = sW[p4 + pi];
      float s = 0.f;
#pragma unroll
      for (int k = 0; k < 32; ++k) s = fmaf(wr[k], qs[k], s);
      o[pi] = s;
    }
    *reinterpret_cast<float4*>(&op[p4]) = make_float4(o[0], o[1], o[2], o[3]);
  }
}

extern "C" void kernel_launch(void* const* d_in, const int* in_sizes, int n_in,
                              void* d_out, int out_size, void* d_ws, size_t ws_size,
                              hipStream_t stream) {
  const float* h = (const float*)d_in[0];
  const int* pmask = (const int*)d_in[1];
  const float* Wk = (const float*)d_in[2];
  const float* Wq = (const float*)d_in[3];
  const float* Wv = (const float*)d_in[4];
  const float* eta = (const float*)d_in[5];
  const float* gamma_p = (const float*)d_in[6];
  float* out = (float*)d_out;
  float* ws = (float*)d_ws;

  // base layout (floats) — identical to the verified R6 baseline (117.97 MB)
  float* z = ws;                               // 8,388,608
  float* v = z + (size_t)8388608;              // 16,777,216
  float* zq = v;                               // alias (v dead after accum)
  float* maxn = v + (size_t)16777216;          // 64
  float* invn = maxn + 64;                     // 64
  float* Gp = invn + 64;                       // 1,048,576
  float* Mp = Gp + (size_t)1048576;            // 1,048,576
  float* Cp = Mp + (size_t)1048576;            // 2,097,152
  float* Wf = Cp + (size_t)2097152;            // 131,072   -> end 29,491,328 floats
  // pre-split extension (75.5 MB): h hi/lo, W hi/lo ([Wk|Wq|Wv] rows)
  u16* hhi = (u16*)(ws + 29491328);            // 16,777,216 u16
  u16* hlo = (u16*)(ws + 37879936);
  u16* whi = (u16*)(ws + 46268544);            // 2,097,152 u16
  u16* wlo = (u16*)(ws + 47317120);            // end 48,365,696 floats = 193,462,784 B
  const bool presplit = (ws_size >= (size_t)193462784);

  if (presplit) {
    split_kernel<<<2048, 256, 0, stream>>>(h, hhi, hlo, 4194304);
    split_kernel<<<512, 256, 0, stream>>>(Wk, whi, wlo, 131072);
    split_kernel<<<512, 256, 0, stream>>>(Wq, whi + 524288, wlo + 524288, 131072);
    split_kernel<<<512, 256, 0, stream>>>(Wv, whi + 1048576, wlo + 1048576, 262144);
    gemm_mfma<true><<<dim3(4, 128), 256, 0, stream>>>(hhi, hlo, whi, wlo, nullptr, nullptr, z, 512);
    gemm_mfma<true><<<dim3(8, 128), 256, 0, stream>>>(hhi, hlo, whi + 1048576, wlo + 1048576,
                                                      nullptr, nullptr, v, 1024);
  } else {
    gemm_mfma<false><<<dim3(4, 128), 256, 0, stream>>>(nullptr, nullptr, nullptr, nullptr, h, Wk, z, 512);
    gemm_mfma<false><<<dim3(8, 128), 256, 0, stream>>>(nullptr, nullptr, nullptr, nullptr, h, Wv, v, 1024);
  }
  norm_kernel<<<64, 256, 0, stream>>>(z, maxn, invn);
  accum_kernel<<<dim3(64, 16), 256, 0, stream>>>(z, v, pmask, invn, Gp, Mp, Cp);
  if (presplit) {
    gemm_mfma<true><<<dim3(4, 128), 256, 0, stream>>>(hhi, hlo, whi + 524288, wlo + 524288,
                                                      nullptr, nullptr, zq, 512);
  } else {
    gemm_mfma<false><<<dim3(4, 128), 256, 0, stream>>>(nullptr, nullptr, nullptr, nullptr, h, Wq, zq, 512);
  }
  solve_kernel<<<64, 64, 0, stream>>>(Gp, Mp, Cp, invn, eta, gamma_p, Wf);
  out_kernel<<<dim3(64, 16), 256, 0, stream>>>(zq, Wf, out);
}

// Round 11
// 661.182 us; speedup vs baseline: 1.9818x; 1.0088x over previous
//
#include <hip/hip_runtime.h>
#include <math.h>

// SKA module: B=4, T=4096, D=1024, H=16, r=32, P=64
// R11: + reduce_kernel (parallel partial-sum) — solve_kernel was latency-bound
//      on its 16MB serial reduction (154us @ 59GB/s, occupancy 0.74%).
#define B_ 4
#define T_ 4096
#define H_ 16
#define R_ 32
#define P_ 64
#define D_ 1024
#define NC_ 16
#define RIDGE 1e-3f

typedef unsigned short u16;
typedef __attribute__((ext_vector_type(8))) short short8;   // 8 bf16 bit-patterns
typedef __attribute__((ext_vector_type(4))) float f32x4;

__device__ __forceinline__ u16 f2bf(float f) {  // RNE float -> bf16 bits
  unsigned int u = __float_as_uint(f);
  unsigned int r = u + 0x7FFFu + ((u >> 16) & 1u);
  return (u16)(r >> 16);
}
__device__ __forceinline__ float bf2f(u16 b) {
  return __uint_as_float(((unsigned int)b) << 16);
}

// ---------- split pass: x(f32) -> hi,lo bf16 bit arrays ----------
__global__ __launch_bounds__(256) void split_kernel(const float* __restrict__ x,
                                                    u16* __restrict__ hi,
                                                    u16* __restrict__ lo, int n4) {
  for (int i = blockIdx.x * 256 + threadIdx.x; i < n4; i += gridDim.x * 256) {
    float4 v = reinterpret_cast<const float4*>(x)[i];
    float xs[4] = {v.x, v.y, v.z, v.w};
    ushort4 hh, ll;
    u16* hp = (u16*)&hh; u16* lp = (u16*)&ll;
#pragma unroll
    for (int j = 0; j < 4; ++j) {
      u16 hb = f2bf(xs[j]);
      hp[j] = hb;
      lp[j] = f2bf(xs[j] - bf2f(hb));
    }
    reinterpret_cast<ushort4*>(hi)[i] = hh;
    reinterpret_cast<ushort4*>(lo)[i] = ll;
  }
}

// ---------- C[M][ldc-slice] = A[M][1024] @ W[N][1024]^T via split-bf16 MFMA --
// PS=true: pre-split bf16 inputs; PS=false: f32 inputs, convert in-kernel.
template <bool PS>
__global__ __launch_bounds__(256) void gemm_mfma(const u16* __restrict__ Ahi,
                                                 const u16* __restrict__ Alo,
                                                 const u16* __restrict__ Whi,
                                                 const u16* __restrict__ Wlo,
                                                 const float* __restrict__ Af,
                                                 const float* __restrict__ Wff,
                                                 float* __restrict__ C, int ldc) {
  __shared__ alignas(16) u16 Ah[128][40];   // +8 pad (2-way bank alias = free)
  __shared__ alignas(16) u16 Al[128][40];
  __shared__ alignas(16) u16 Bh[128][40];
  __shared__ alignas(16) u16 Bl[128][40];
  const int tid = threadIdx.x;
  const int lane = tid & 63;
  const int wave = tid >> 6;                 // 4 waves
  const int wm = wave >> 1, wn = wave & 1;   // 2x2 wave grid, 64x64 each
  const int m0 = blockIdx.y * 128, n0 = blockIdx.x * 128;
  const int fr = lane & 15;                  // fragment row (A) / col (B)
  const int fk = (lane >> 4) * 8;            // fragment k base
  f32x4 acc[4][4] = {};

  for (int k0 = 0; k0 < 1024; k0 += 32) {
    if constexpr (PS) {
#pragma unroll
      for (int it = 0; it < 2; ++it) {
        int s = tid + it * 256;              // 512 slots: 128 rows x 4 groups
        int r = s >> 2, c = (s & 3) * 8;
        size_t ga = (size_t)(m0 + r) * 1024 + k0 + c;
        size_t gw = (size_t)(n0 + r) * 1024 + k0 + c;
        *reinterpret_cast<uint4*>(&Ah[r][c]) = *reinterpret_cast<const uint4*>(&Ahi[ga]);
        *reinterpret_cast<uint4*>(&Al[r][c]) = *reinterpret_cast<const uint4*>(&Alo[ga]);
        *reinterpret_cast<uint4*>(&Bh[r][c]) = *reinterpret_cast<const uint4*>(&Whi[gw]);
        *reinterpret_cast<uint4*>(&Bl[r][c]) = *reinterpret_cast<const uint4*>(&Wlo[gw]);
      }
    } else {
#pragma unroll
      for (int it = 0; it < 4; ++it) {
        int s = tid + it * 256;              // 1024 slots: 128 rows x 8 groups
        int r = s >> 3, c = (s & 7) * 4;
        float4 av = *reinterpret_cast<const float4*>(&Af[(size_t)(m0 + r) * 1024 + k0 + c]);
        float4 wv = *reinterpret_cast<const float4*>(&Wff[(size_t)(n0 + r) * 1024 + k0 + c]);
        float ax[4] = {av.x, av.y, av.z, av.w};
        float wx[4] = {wv.x, wv.y, wv.z, wv.w};
#pragma unroll
        for (int j = 0; j < 4; ++j) {
          u16 hb = f2bf(ax[j]);
          Ah[r][c + j] = hb;
          Al[r][c + j] = f2bf(ax[j] - bf2f(hb));
          u16 wb = f2bf(wx[j]);
          Bh[r][c + j] = wb;
          Bl[r][c + j] = f2bf(wx[j] - bf2f(wb));
        }
      }
    }
    __syncthreads();
    short8 ah[4], al[4];
#pragma unroll
    for (int mi = 0; mi < 4; ++mi) {
      ah[mi] = *reinterpret_cast<const short8*>(&Ah[wm * 64 + mi * 16 + fr][fk]);
      al[mi] = *reinterpret_cast<const short8*>(&Al[wm * 64 + mi * 16 + fr][fk]);
    }
#pragma unroll
    for (int ni = 0; ni < 4; ++ni) {
      short8 bh = *reinterpret_cast<const short8*>(&Bh[wn * 64 + ni * 16 + fr][fk]);
      short8 bl = *reinterpret_cast<const short8*>(&Bl[wn * 64 + ni * 16 + fr][fk]);
#pragma unroll
      for (int mi = 0; mi < 4; ++mi) {
        acc[mi][ni] = __builtin_amdgcn_mfma_f32_16x16x32_bf16(ah[mi], bh, acc[mi][ni], 0, 0, 0);
        acc[mi][ni] = __builtin_amdgcn_mfma_f32_16x16x32_bf16(al[mi], bh, acc[mi][ni], 0, 0, 0);
        acc[mi][ni] = __builtin_amdgcn_mfma_f32_16x16x32_bf16(ah[mi], bl, acc[mi][ni], 0, 0, 0);
      }
    }
    __syncthreads();
  }
  const int cr = (lane >> 4) * 4;            // C/D: col=lane&15, row=(lane>>4)*4+reg
#pragma unroll
  for (int mi = 0; mi < 4; ++mi)
#pragma unroll
    for (int ni = 0; ni < 4; ++ni)
#pragma unroll
      for (int rr = 0; rr < 4; ++rr)
        C[(size_t)(m0 + wm * 64 + mi * 16 + cr + rr) * ldc + (n0 + wn * 64 + ni * 16 + fr)] =
            acc[mi][ni][rr];
}

// ---------- per-(b,h) max over T of ||z_raw[t]||, clipped ----------
__global__ __launch_bounds__(256) void norm_kernel(const float* __restrict__ z,
                                                   float* __restrict__ maxn,
                                                   float* __restrict__ invn) {
  const int bh = blockIdx.x;
  const int b = bh >> 4, hh = bh & 15;
  const size_t zb = (size_t)b * T_ * (H_ * R_) + (size_t)hh * R_;
  float mx = 0.f;
  for (int t = threadIdx.x; t < T_; t += 256) {
    const float4* p = reinterpret_cast<const float4*>(&z[zb + (size_t)t * (H_ * R_)]);
    float s = 0.f;
#pragma unroll
    for (int j = 0; j < 8; ++j) {
      float4 q = p[j];
      s = fmaf(q.x, q.x, s); s = fmaf(q.y, q.y, s);
      s = fmaf(q.z, q.z, s); s = fmaf(q.w, q.w, s);
    }
    mx = fmaxf(mx, s);
  }
  __shared__ float red[256];
  red[threadIdx.x] = mx;
  __syncthreads();
  for (int s = 128; s > 0; s >>= 1) {
    if (threadIdx.x < s) red[threadIdx.x] = fmaxf(red[threadIdx.x], red[threadIdx.x + s]);
    __syncthreads();
  }
  if (threadIdx.x == 0) {
    float mn = fmaxf(sqrtf(red[0]), 1e-6f);
    maxn[bh] = mn;
    invn[bh] = 1.f / mn;
  }
}

// ---------- per-(b,h,chunk): partial G (32x32), M_cov (32x32), C_v (64x32) --
__global__ __launch_bounds__(256) void accum_kernel(const float* __restrict__ z,
                                                    const float* __restrict__ v,
                                                    const int* __restrict__ pmask,
                                                    const float* __restrict__ invn,
                                                    float* __restrict__ Gp,
                                                    float* __restrict__ Mp,
                                                    float* __restrict__ Cp) {
  const int bh = blockIdx.x;
  const int chunk = blockIdx.y;
  const int b = bh >> 4, hh = bh & 15;
  const int tid = threadIdx.x;
  __shared__ alignas(16) float zs[65][32];
  __shared__ alignas(16) float vs[64][64];
  __shared__ float ms[65];
  const float inv = invn[bh];
  const int r_gm = tid >> 3;
  const int s0 = (tid & 7) * 4;
  const int p0 = (tid & 7) * 8;
  float accG[4] = {0.f, 0.f, 0.f, 0.f};
  float accM[4] = {0.f, 0.f, 0.f, 0.f};
  float accC[8] = {0.f, 0.f, 0.f, 0.f, 0.f, 0.f, 0.f, 0.f};
  const size_t zb = (size_t)b * T_ * (H_ * R_) + (size_t)hh * R_;
  const size_t vb = (size_t)b * T_ * (H_ * P_) + (size_t)hh * P_;
  const int tstart = chunk * 256;
  for (int tile = 0; tile < 4; ++tile) {
    const int t0 = tstart + tile * 64;
    for (int idx = tid; idx < 65 * 32; idx += 256) {
      int i = idx >> 5, r = idx & 31;
      int t = t0 - 1 + i;
      zs[i][r] = (t >= 0) ? z[zb + (size_t)t * (H_ * R_) + r] * inv : 0.f;
    }
    if (tid < 65) {
      int t = t0 - 1 + tid;
      ms[tid] = (t >= 0) ? (float)pmask[b * T_ + t] : 0.f;
    }
    for (int idx = tid; idx < 64 * 64; idx += 256) {
      int i = idx >> 6, p = idx & 63;
      vs[i][p] = v[vb + (size_t)(t0 + i) * (H_ * P_) + p];
    }
    __syncthreads();
    float4 prev = *reinterpret_cast<const float4*>(&zs[0][s0]);
    for (int i = 1; i <= 64; ++i) {
      float mc = ms[i];
      float ml = mc * ms[i - 1];
      float zr = zs[i][r_gm];
      float4 cur = *reinterpret_cast<const float4*>(&zs[i][s0]);
      float gz = mc * zr;
      float mz = ml * zr;
      accG[0] = fmaf(gz, cur.x, accG[0]);
      accG[1] = fmaf(gz, cur.y, accG[1]);
      accG[2] = fmaf(gz, cur.z, accG[2]);
      accG[3] = fmaf(gz, cur.w, accG[3]);
      accM[0] = fmaf(mz, prev.x, accM[0]);
      accM[1] = fmaf(mz, prev.y, accM[1]);
      accM[2] = fmaf(mz, prev.z, accM[2]);
      accM[3] = fmaf(mz, prev.w, accM[3]);
      float4 va = *reinterpret_cast<const float4*>(&vs[i - 1][p0]);
      float4 vb4 = *reinterpret_cast<const float4*>(&vs[i - 1][p0 + 4]);
      accC[0] = fmaf(gz, va.x, accC[0]);
      accC[1] = fmaf(gz, va.y, accC[1]);
      accC[2] = fmaf(gz, va.z, accC[2]);
      accC[3] = fmaf(gz, va.w, accC[3]);
      accC[4] = fmaf(gz, vb4.x, accC[4]);
      accC[5] = fmaf(gz, vb4.y, accC[5]);
      accC[6] = fmaf(gz, vb4.z, accC[6]);
      accC[7] = fmaf(gz, vb4.w, accC[7]);
      prev = cur;
    }
    __syncthreads();
  }
  const size_t base = (size_t)bh * NC_ + chunk;
  *reinterpret_cast<float4*>(&Gp[base * 1024 + r_gm * 32 + s0]) =
      make_float4(accG[0], accG[1], accG[2], accG[3]);
  *reinterpret_cast<float4*>(&Mp[base * 1024 + r_gm * 32 + s0]) =
      make_float4(accM[0], accM[1], accM[2], accM[3]);
#pragma unroll
  for (int j = 0; j < 8; ++j) Cp[base * 2048 + (size_t)(p0 + j) * 32 + r_gm] = accC[j];
}

// ---------- parallel partial-sum: Gp/Mp/Cp (16 chunks) -> Gr/Mr/Cr ----------
// Same c-ascending order as the old in-solve reduction => bitwise identical.
__global__ __launch_bounds__(256) void reduce_kernel(const float* __restrict__ Gp,
                                                     const float* __restrict__ Mp,
                                                     const float* __restrict__ Cp,
                                                     float* __restrict__ Gr,
                                                     float* __restrict__ Mr,
                                                     float* __restrict__ Cr) {
  const int bh = blockIdx.x;
  const int tid = threadIdx.x;
  const size_t gb = (size_t)bh * NC_ * 1024;
  const size_t cb = (size_t)bh * NC_ * 2048;
  for (int e = tid; e < 1024; e += 256) {
    float a = 0.f, m = 0.f;
    for (int c = 0; c < NC_; ++c) {
      a += Gp[gb + (size_t)c * 1024 + e];
      m += Mp[gb + (size_t)c * 1024 + e];
    }
    Gr[(size_t)bh * 1024 + e] = a;
    Mr[(size_t)bh * 1024 + e] = m;
  }
  for (int e = tid; e < 2048; e += 256) {
    float a = 0.f;
    for (int c = 0; c < NC_; ++c) a += Cp[cb + (size_t)c * 2048 + e];
    Cr[(size_t)bh * 2048 + e] = a;
  }
}

// ---------- per-(b,h): Cholesky, solves, power iter -> W_final (64x32) ----
__global__ __launch_bounds__(64) void solve_kernel(const float* __restrict__ Gr,
                                                   const float* __restrict__ Mr,
                                                   const float* __restrict__ Cr,
                                                   const float* __restrict__ invn,
                                                   const float* __restrict__ p_eta,
                                                   const float* __restrict__ p_gamma,
                                                   float* __restrict__ Wf) {
  const int bh = blockIdx.x;
  const int tid = threadIdx.x;
  __shared__ float sG[32][32], sL[32][32], sB1[32][32], sB2[32][32], sA[32][32], sF[32][32];
  __shared__ float sCv[64][32];
  __shared__ float t2a[32][64], t3a[32][64];
  __shared__ float vec1[32], vec2[32];
  __shared__ float scal[2];
  for (int idx = tid; idx < 1024; idx += 64) {
    sG[idx >> 5][idx & 31] = Gr[(size_t)bh * 1024 + idx];
    sB1[idx >> 5][idx & 31] = Mr[(size_t)bh * 1024 + idx];
  }
  for (int idx = tid; idx < 2048; idx += 64) {
    sCv[idx >> 5][idx & 31] = Cr[(size_t)bh * 2048 + idx];
  }
  __syncthreads();
  if (tid < 32) sG[tid][tid] += RIDGE;
  __syncthreads();
  for (int idx = tid; idx < 1024; idx += 64) {
    int r = idx >> 5, c = idx & 31;
    sL[r][c] = (c <= r) ? sG[r][c] : 0.f;
  }
  __syncthreads();
  for (int j = 0; j < 32; ++j) {
    if (tid == 0) {
      float s = sL[j][j];
      for (int k = 0; k < j; ++k) s -= sL[j][k] * sL[j][k];
      sL[j][j] = sqrtf(s);
    }
    __syncthreads();
    if (tid > j && tid < 32) {
      float s = sL[tid][j];
      for (int k = 0; k < j; ++k) s -= sL[tid][k] * sL[j][k];
      sL[tid][j] = s / sL[j][j];
    }
    __syncthreads();
  }
  if (tid < 32) {
    int c = tid;
    for (int i = 0; i < 32; ++i) {
      float s = sB1[i][c];
      for (int k = 0; k < i; ++k) s -= sL[i][k] * sB2[k][c];
      sB2[i][c] = s / sL[i][i];
    }
  }
  __syncthreads();
  for (int idx = tid; idx < 1024; idx += 64) {
    int r = idx >> 5, c = idx & 31;
    sB1[r][c] = sB2[c][r];
  }
  __syncthreads();
  if (tid < 32) {
    int c = tid;
    for (int i = 0; i < 32; ++i) {
      float s = sB1[i][c];
      for (int k = 0; k < i; ++k) s -= sL[i][k] * sB2[k][c];
      sB2[i][c] = s / sL[i][i];
    }
  }
  __syncthreads();
  for (int idx = tid; idx < 1024; idx += 64) {
    int r = idx >> 5, c = idx & 31;
    sA[r][c] = sB2[c][r];
  }
  __syncthreads();
  if (tid < 32) vec1[tid] = 0.17677669529663687f;
  __syncthreads();
  for (int it = 0; it < 6; ++it) {
    if (tid < 32) {
      float s = 0.f;
      for (int k = 0; k < 32; ++k) s += sA[tid][k] * vec1[k];
      vec2[tid] = s;
    }
    __syncthreads();
    if (tid == 0) {
      float s = 0.f;
      for (int k = 0; k < 32; ++k) s += vec2[k] * vec2[k];
      scal[0] = fmaxf(sqrtf(s), 1e-8f);
    }
    __syncthreads();
    if (tid < 32) vec2[tid] = vec2[tid] / scal[0];
    __syncthreads();
    if (tid < 32) {
      float s = 0.f;
      for (int k = 0; k < 32; ++k) s += sA[k][tid] * vec2[k];
      vec1[tid] = s;
    }
    __syncthreads();
    if (tid == 0) {
      float s = 0.f;
      for (int k = 0; k < 32; ++k) s += vec1[k] * vec1[k];
      scal[0] = fmaxf(sqrtf(s), 1e-8f);
    }
    __syncthreads();
    if (tid < 32) vec1[tid] = vec1[tid] / scal[0];
    __syncthreads();
  }
  if (tid < 32) {
    float s = 0.f;
    for (int k = 0; k < 32; ++k) s += sA[tid][k] * vec1[k];
    vec2[tid] = s;
  }
  __syncthreads();
  if (tid == 0) {
    float s = 0.f;
    for (int k = 0; k < 32; ++k) s += vec2[k] * vec2[k];
    scal[1] = fmaxf(sqrtf(s), 1.f);
  }
  __syncthreads();
  {
    float gc = fminf(fmaxf(p_gamma[0], 1.f), 1.5f);
    float fct = gc / scal[1];
    for (int idx = tid; idx < 1024; idx += 64) sA[idx >> 5][idx & 31] *= fct;
  }
  __syncthreads();
  for (int e = tid; e < 1024; e += 64) {
    int i = e >> 5, j = e & 31;
    float s = 0.f;
    for (int k = 0; k < 32; ++k) s += sA[i][k] * sA[k][j];
    sF[i][j] = s;
  }
  __syncthreads();
  for (int e = tid; e < 1024; e += 64) {
    int i = e >> 5, j = e & 31;
    float s = 0.f;
    for (int k = 0; k <= i; ++k) s += sL[i][k] * sF[k][j];
    sB1[i][j] = s;
  }
  __syncthreads();
  if (tid < 32) {
    int c = tid;
    for (int i = 31; i >= 0; --i) {
      float s = sB1[c][i];
      for (int k = i + 1; k < 32; ++k) s -= sL[k][i] * sB2[k][c];
      sB2[i][c] = s / sL[i][i];
    }
  }
  __syncthreads();
  {
    int p = tid;
    for (int i = 0; i < 32; ++i) {
      float s = sCv[p][i];
      for (int k = 0; k < i; ++k) s -= sL[i][k] * t2a[k][p];
      t2a[i][p] = s / sL[i][i];
    }
  }
  __syncthreads();
  {
    int p = tid;
    for (int i = 31; i >= 0; --i) {
      float s = t2a[i][p];
      for (int k = i + 1; k < 32; ++k) s -= sL[k][i] * t3a[k][p];
      t3a[i][p] = s / sL[i][i];
    }
  }
  __syncthreads();
  {
    float so = p_eta[0] * invn[bh];
    int p = tid;
    for (int j = 0; j < 32; ++j) {
      float s = 0.f;
      for (int r = 0; r < 32; ++r) s += t3a[r][p] * sB2[j][r];
      Wf[(size_t)bh * 2048 + p * 32 + j] = s * so;
    }
  }
}

// ---------- y[b,t,h,:] = W_final[b,h] (64x32) @ zq_raw[b,t,h,:] ----------
__global__ __launch_bounds__(256) void out_kernel(const float* __restrict__ zq,
                                                  const float* __restrict__ Wf,
                                                  float* __restrict__ out) {
  const int bh = blockIdx.x;
  const int chunk = blockIdx.y;
  const int b = bh >> 4, hh = bh & 15;
  const int tid = threadIdx.x;
  __shared__ alignas(16) float sW[64][32];
  for (int idx = tid; idx < 2048; idx += 256) sW[idx >> 5][idx & 31] = Wf[(size_t)bh * 2048 + idx];
  __syncthreads();
  const int t = chunk * 256 + tid;
  const float4* qp = reinterpret_cast<const float4*>(&zq[((size_t)(b * T_ + t) * H_ + hh) * R_]);
  float qs[32];
#pragma unroll
  for (int j = 0; j < 8; ++j) {
    float4 q = qp[j];
    qs[j * 4 + 0] = q.x; qs[j * 4 + 1] = q.y; qs[j * 4 + 2] = q.z; qs[j * 4 + 3] = q.w;
  }
  float* op = &out[((size_t)(b * T_ + t) * H_ + hh) * P_];
  for (int p4 = 0; p4 < 64; p4 += 4) {
    float o[4];
#pragma unroll
    for (int pi = 0; pi < 4; ++pi) {
      const float* wr = sW[p4 + pi];
      float s = 0.f;
#pragma unroll
      for (int k = 0; k < 32; ++k) s = fmaf(wr[k], qs[k], s);
      o[pi] = s;
    }
    *reinterpret_cast<float4*>(&op[p4]) = make_float4(o[0], o[1], o[2], o[3]);
  }
}

extern "C" void kernel_launch(void* const* d_in, const int* in_sizes, int n_in,
                              void* d_out, int out_size, void* d_ws, size_t ws_size,
                              hipStream_t stream) {
  const float* h = (const float*)d_in[0];
  const int* pmask = (const int*)d_in[1];
  const float* Wk = (const float*)d_in[2];
  const float* Wq = (const float*)d_in[3];
  const float* Wv = (const float*)d_in[4];
  const float* eta = (const float*)d_in[5];
  const float* gamma_p = (const float*)d_in[6];
  float* out = (float*)d_out;
  float* ws = (float*)d_ws;

  // base layout (floats) — identical to the verified R10 layout (117.97 MB)
  float* z = ws;                               // 8,388,608
  float* v = z + (size_t)8388608;              // 16,777,216
  float* zq = v;                               // alias (v dead after accum)
  float* maxn = v + (size_t)16777216;          // 64
  float* invn = maxn + 64;                     // 64
  float* Gp = invn + 64;                       // 1,048,576
  float* Mp = Gp + (size_t)1048576;            // 1,048,576
  float* Cp = Mp + (size_t)1048576;            // 2,097,152
  float* Wf = Cp + (size_t)2097152;            // 131,072   -> end 29,491,328 floats
  // reduced partials overlay the z slot (z is dead after accum_kernel)
  float* Gr = z;                               // 65,536
  float* Mr = z + 65536;                       // 65,536
  float* Cr = z + 131072;                      // 131,072 (total 1 MB << z's 32 MB)
  // pre-split extension (75.5 MB): h hi/lo, W hi/lo ([Wk|Wq|Wv] rows)
  u16* hhi = (u16*)(ws + 29491328);            // 16,777,216 u16
  u16* hlo = (u16*)(ws + 37879936);
  u16* whi = (u16*)(ws + 46268544);            // 2,097,152 u16
  u16* wlo = (u16*)(ws + 47317120);            // end 48,365,696 floats = 193,462,784 B
  const bool presplit = (ws_size >= (size_t)193462784);

  if (presplit) {
    split_kernel<<<2048, 256, 0, stream>>>(h, hhi, hlo, 4194304);
    split_kernel<<<512, 256, 0, stream>>>(Wk, whi, wlo, 131072);
    split_kernel<<<512, 256, 0, stream>>>(Wq, whi + 524288, wlo + 524288, 131072);
    split_kernel<<<512, 256, 0, stream>>>(Wv, whi + 1048576, wlo + 1048576, 262144);
    gemm_mfma<true><<<dim3(4, 128), 256, 0, stream>>>(hhi, hlo, whi, wlo, nullptr, nullptr, z, 512);
    gemm_mfma<true><<<dim3(8, 128), 256, 0, stream>>>(hhi, hlo, whi + 1048576, wlo + 1048576,
                                                      nullptr, nullptr, v, 1024);
  } else {
    gemm_mfma<false><<<dim3(4, 128), 256, 0, stream>>>(nullptr, nullptr, nullptr, nullptr, h, Wk, z, 512);
    gemm_mfma<false><<<dim3(8, 128), 256, 0, stream>>>(nullptr, nullptr, nullptr, nullptr, h, Wv, v, 1024);
  }
  norm_kernel<<<64, 256, 0, stream>>>(z, maxn, invn);
  accum_kernel<<<dim3(64, 16), 256, 0, stream>>>(z, v, pmask, invn, Gp, Mp, Cp);
  reduce_kernel<<<64, 256, 0, stream>>>(Gp, Mp, Cp, Gr, Mr, Cr);   // z now dead
  if (presplit) {
    gemm_mfma<true><<<dim3(4, 128), 256, 0, stream>>>(hhi, hlo, whi + 524288, wlo + 524288,
                                                      nullptr, nullptr, zq, 512);
  } else {
    gemm_mfma<false><<<dim3(4, 128), 256, 0, stream>>>(nullptr, nullptr, nullptr, nullptr, h, Wq, zq, 512);
  }
  solve_kernel<<<64, 64, 0, stream>>>(Gr, Mr, Cr, invn, eta, gamma_p, Wf);
  out_kernel<<<dim3(64, 16), 256, 0, stream>>>(zq, Wf, out);
}